// Round 7
// baseline (186.384 us; speedup 1.0000x reference)
//
#include <hip/hip_runtime.h>
#include <cstdint>
#include <cstddef>

// Problem constants
#define BB  4
#define QQ  2048
#define SK  2048   // key length
#define DD  512
#define HH  8
#define DHH 64
#define CS  16     // K-tiles (of 64 keys) per attention chunk
#define ZMAX 2     // max chunks (nkt <= 32)

typedef __bf16 bf16;
typedef bf16  bf16x8 __attribute__((ext_vector_type(8)));
typedef bf16  bf16x4 __attribute__((ext_vector_type(4)));
typedef float f32x4  __attribute__((ext_vector_type(4)));
typedef _Float16 f16;
typedef f16   f16x4 __attribute__((ext_vector_type(4)));
typedef f16   f16x8 __attribute__((ext_vector_type(8)));

// ---- async global->LDS 16B copy (wave-uniform base + lane*16 semantics) ----
__device__ __forceinline__ void async16(void* lds, const void* g) {
  __builtin_amdgcn_global_load_lds(
      (const __attribute__((address_space(1))) unsigned int*)g,
      (__attribute__((address_space(3))) unsigned int*)lds, 16, 0, 0);
}

// pack two positive f32 into one u32 of 2 bf16 (truncation) via v_perm_b32
__device__ __forceinline__ uint32_t pk2(float lo, float hi) {
  return __builtin_amdgcn_perm(__builtin_bit_cast(uint32_t, hi),
                               __builtin_bit_cast(uint32_t, lo), 0x07060302u);
}

// ---- GEMM body: D[m][n] = sum_k A[m][k]*B[n][k], K=512, BK=64 ----
// m97-style SINGLE buffer, 2 barriers/iter, 32 KB LDS -> 3 blocks/CU.
// M-tile = MT*32, N-tile = 128. 4 waves (2x2). XOR-swizzled LDS.
// A_F32/B_F32: operand is f32 in global; staged via load+RNE-cvt+ds_write
// (identical numerics to a pre-convert pass). Otherwise bf16 via async16.
template <int MT, bool A_F32, bool B_F32, typename EpiF>
__device__ __forceinline__ void gemm_body(
    const void* __restrict__ A, const void* __restrict__ B,
    int tM, int tN, EpiF epi_fn) {
  __shared__ __align__(16) bf16 lA[MT * 32 * 64];
  __shared__ __align__(16) bf16 lB[128 * 64];
  const int tid  = threadIdx.x;
  const int l    = tid & 63;
  const int w    = tid >> 6;
  const int lrow = l & 15, lq = l >> 4;
  const int wm = (w >> 1) * (MT * 16), wn = (w & 1) * 64;

  f32x4 acc[MT][4] = {};
  for (int it = 0; it < 8; ++it) {
    const int kt = it * 64;
    if (it) __syncthreads();             // protect LDS from prev readers
#pragma unroll
    for (int j = 0; j < MT; ++j) {
      int c = j * 256 + tid, row = c >> 3, gcc = (c & 7) ^ (row & 7);
      size_t off = (size_t)(tM + row) * DD + kt + gcc * 8;
      if (A_F32) {
        const float* src = (const float*)A + off;
        float4 a0 = *(const float4*)src, a1 = *(const float4*)(src + 4);
        bf16x8 o;
        o[0] = (bf16)a0.x; o[1] = (bf16)a0.y; o[2] = (bf16)a0.z; o[3] = (bf16)a0.w;
        o[4] = (bf16)a1.x; o[5] = (bf16)a1.y; o[6] = (bf16)a1.z; o[7] = (bf16)a1.w;
        *(bf16x8*)&lA[c * 8] = o;
      } else {
        async16(&lA[c * 8], (const bf16*)A + off);
      }
    }
#pragma unroll
    for (int j = 0; j < 4; ++j) {
      int c = j * 256 + tid, row = c >> 3, gcc = (c & 7) ^ (row & 7);
      size_t off = (size_t)(tN + row) * DD + kt + gcc * 8;
      if (B_F32) {
        const float* src = (const float*)B + off;
        float4 a0 = *(const float4*)src, a1 = *(const float4*)(src + 4);
        bf16x8 o;
        o[0] = (bf16)a0.x; o[1] = (bf16)a0.y; o[2] = (bf16)a0.z; o[3] = (bf16)a0.w;
        o[4] = (bf16)a1.x; o[5] = (bf16)a1.y; o[6] = (bf16)a1.z; o[7] = (bf16)a1.w;
        *(bf16x8*)&lB[c * 8] = o;
      } else {
        async16(&lB[c * 8], (const bf16*)B + off);
      }
    }
    __syncthreads();                     // drains vmcnt+lgkm -> LDS valid

#pragma unroll
    for (int ks = 0; ks < 2; ++ks) {
      bf16x8 af[MT], bfr[4];
#pragma unroll
      for (int mt = 0; mt < MT; ++mt) {
        int row = wm + mt * 16 + lrow;
        int chunk = row * 8 + ((ks * 4 + lq) ^ (lrow & 7));
        af[mt] = *(const bf16x8*)&lA[chunk * 8];
      }
#pragma unroll
      for (int nt = 0; nt < 4; ++nt) {
        int row = wn + nt * 16 + lrow;
        int chunk = row * 8 + ((ks * 4 + lq) ^ (lrow & 7));
        bfr[nt] = *(const bf16x8*)&lB[chunk * 8];
      }
#pragma unroll
      for (int mt = 0; mt < MT; ++mt)
#pragma unroll
        for (int nt = 0; nt < 4; ++nt)
          acc[mt][nt] = __builtin_amdgcn_mfma_f32_16x16x32_bf16(
              af[mt], bfr[nt], acc[mt][nt], 0, 0, 0);
    }
  }

#pragma unroll
  for (int mt = 0; mt < MT; ++mt)
#pragma unroll
    for (int nt = 0; nt < 4; ++nt) {
      int row0 = tM + wm + mt * 16 + lq * 4;
      int col  = tN + wn + nt * 16 + lrow;
      epi_fn(acc[mt][nt], row0, col);
    }
}

// fused Q/K/V projections from RAW f32 inputs, blockIdx.y selects.
// z<2 (Q,K): SWAPPED orientation, A=W f32 (m=out-dim), B=X f32 (n=token).
//   C rows = out-dim -> 4 consecutive dh per lane -> bf16x4 stores.
// z==2 (V): normal, A=X f32 (m=token), B=W f32. C rows = keys -> bf16x4
//   stores to PV-ready-permuted [B,H,DH,S].
__global__ __launch_bounds__(256, 3) void proj3(
    const float* __restrict__ xq, const float* __restrict__ wq, bf16* __restrict__ qh,
    const float* __restrict__ xk, const float* __restrict__ wk, bf16* __restrict__ kh,
    const float* __restrict__ xv, const float* __restrict__ wv, bf16* __restrict__ vt,
    float qscale) {
  const int z = blockIdx.y, x = blockIdx.x;
  if (z < 2) {
    const float* A = z == 0 ? wq : wk;   // weights: m = out-dim
    const float* B = z == 0 ? xq : xk;   // activations: n = token
    bf16* Cout     = z == 0 ? qh : kh;
    const float scale = z == 0 ? qscale : 1.0f;
    int tM = (x & 3) * 128, tN = (x >> 2) * 128;
    gemm_body<4, true, true>(A, B, tM, tN,
        [&](const f32x4& a, int row0, int col) {
      int b2 = col >> 11, s = col & 2047;      // token
      int h2 = row0 >> 6, dh0 = row0 & 63;     // out-dim (4 consecutive dh)
      bf16x4 o;
#pragma unroll
      for (int r = 0; r < 4; ++r) o[r] = (bf16)(a[r] * scale);
      *(bf16x4*)&Cout[((size_t)(b2 * HH + h2) * QQ + s) * DHH + dh0] = o;
    });
  } else {
    int tM = (x >> 2) * 128, tN = (x & 3) * 128;
    gemm_body<4, true, true>(xv, wv, tM, tN,
        [&](const f32x4& a, int row0, int col) {
      int b2 = row0 >> 11, s0 = row0 & 2047;   // 4 consecutive keys
      int h2 = col >> 6,  dh = col & 63;
      int tile = s0 >> 6, kk = s0 & 63;
      int g = kk >> 4, a2 = (kk >> 2) & 3;
      int idx0 = ((g >> 1) * 4 + a2) * 8 + (g & 1) * 4;   // PV permutation
      bf16x4 o;
#pragma unroll
      for (int r = 0; r < 4; ++r) o[r] = (bf16)a[r];
      *(bf16x4*)&vt[((size_t)(b2 * HH + h2) * DHH + dh) * SK + tile * 64 + idx0] = o;
    });
  }
}

// output projection, SWAPPED: A=W_o f32 (m=out-col), B=ao bf16 (n=token).
// C rows = out-cols -> float4 stores to d_out [token][512].
__global__ __launch_bounds__(256, 3) void proj_o(
    const float* __restrict__ wo, const bf16* __restrict__ ao,
    float* __restrict__ Cout) {
  const int x = blockIdx.x;
  int tM = (x & 7) * 64, tN = (x >> 3) * 128;
  gemm_body<2, true, false>(wo, ao, tM, tN,
      [&](const f32x4& a, int row0, int col) {
    *(float4*)&Cout[(size_t)col * DD + row0] = *(const float4*)&a;
  });
}

// ---- Attention, fixed-size chunks: S^T = K·Q^T, no-max softmax ----
// grid (bh, qt=16, z=2). Block = 128 queries (32/wave), chunk = CS 64-key
// tiles. No shuffles/rescale in loop; P packed via v_perm truncation and
// stays in registers; V is PV-ready so its A-frag is one ds_read_b128.
__global__ __launch_bounds__(256, 4) void attn_split(
    const bf16* __restrict__ qh, const bf16* __restrict__ kh,
    const bf16* __restrict__ vt, const int* __restrict__ valid_lens,
    f16* __restrict__ opart, float* __restrict__ lpart) {
  __shared__ __align__(16) bf16 lK[2][64 * 64];   // [key][dh], swizzled
  __shared__ __align__(16) bf16 lV[2][64 * 64];   // [dh][key-permuted], swizzled
  const int tid  = threadIdx.x;
  const int l    = tid & 63;
  const int w    = tid >> 6;
  const int lrow = l & 15, lq = l >> 4;
  const int rx   = lrow & 7;
  const int bh = blockIdx.x;
  const int b = bh >> 3;
  const int qt = blockIdx.y, z = blockIdx.z;
  const int vl  = valid_lens[b];
  const int nkt = (vl + 63) >> 6;
  const int kt0 = z * CS;
  const int kt1 = min(nkt, kt0 + CS);
  const size_t pbase = ((size_t)bh * 16 + qt) * ZMAX + z;
  float* lout = lpart + pbase * 128;
  f16*   oout = opart + pbase * 8192;

  if (kt0 >= kt1) {                      // empty chunk (block-uniform)
    if (tid < 128) lout[tid] = 0.f;
    return;
  }

  const int q0 = qt * 128 + w * 32;
  const bf16* qbase = qh + (size_t)bh * QQ * DHH;
  const bf16* kbase = kh + (size_t)bh * SK * DHH;
  const bf16* vbase = vt + (size_t)bh * DHH * SK;

  // Q fragments (B-operand: n=lane&15=query, k=quad*8+j), 2 query groups
  bf16x8 qf[2][2];
#pragma unroll
  for (int g = 0; g < 2; ++g)
#pragma unroll
    for (int ks = 0; ks < 2; ++ks)
      qf[g][ks] = *(const bf16x8*)
          &qbase[(size_t)(q0 + g * 16 + lrow) * DHH + ks * 32 + lq * 8];

  auto stageKV = [&](int k0, int buf) {
#pragma unroll
    for (int j = 0; j < 2; ++j) {
      int c = j * 256 + tid, row = c >> 3, gcc = (c & 7) ^ (row & 7);
      async16(&lK[buf][c * 8], &kbase[(size_t)(k0 + row) * DHH + gcc * 8]);
    }
#pragma unroll
    for (int j = 0; j < 2; ++j) {
      int c = j * 256 + tid, row = c >> 3, gcc = (c & 7) ^ (row & 7);
      async16(&lV[buf][c * 8], &vbase[(size_t)row * SK + k0 + gcc * 8]);
    }
  };

  f32x4 acc[2][4] = {};                  // O^T[dh=mt*16+lq*4+r][q group g]
  float rs[2] = {0.f, 0.f};

  stageKV(kt0 * 64, kt0 & 1);
  for (int kt = kt0; kt < kt1; ++kt) {
    __syncthreads();                     // drains stage(kt)
    if (kt + 1 < kt1) stageKV((kt + 1) * 64, (kt + 1) & 1);
    const bf16* bufK = lK[kt & 1];
    const bf16* bufV = lV[kt & 1];
    const int k0 = kt * 64;

    // S^T = K · Q^T (A = K rows; kf shared across both query groups)
    f32x4 s[2][4] = {};
#pragma unroll
    for (int ks = 0; ks < 2; ++ks) {
#pragma unroll
      for (int t = 0; t < 4; ++t) {
        int row = t * 16 + lrow;
        int chunkc = row * 8 + ((ks * 4 + lq) ^ rx);
        bf16x8 kf = *(const bf16x8*)&bufK[chunkc * 8];
#pragma unroll
        for (int g = 0; g < 2; ++g)
          s[g][t] = __builtin_amdgcn_mfma_f32_16x16x32_bf16(
              kf, qf[g][ks], s[g][t], 0, 0, 0);
      }
    }

    if (vl < k0 + 64) {                  // partial tile only: mask
#pragma unroll
      for (int t = 0; t < 4; ++t) {
        int kb = k0 + t * 16 + lq * 4;
#pragma unroll
        for (int r = 0; r < 4; ++r)
          if (kb + r >= vl) { s[0][t][r] = -1e30f; s[1][t][r] = -1e30f; }
      }
    }

    // p = exp2(s) directly (|s| small; masked -> exactly 0)
#pragma unroll
    for (int g = 0; g < 2; ++g)
#pragma unroll
      for (int t = 0; t < 4; ++t)
#pragma unroll
        for (int r = 0; r < 4; ++r) {
          float p = __builtin_amdgcn_exp2f(s[g][t][r]);
          rs[g] += p;
          s[g][t][r] = p;
        }

    // O^T += V^T · P  (vt PV-ready; vf shared across query groups)
#pragma unroll
    for (int p2 = 0; p2 < 2; ++p2) {
      union { bf16x8 v; uint32_t u[4]; } pb[2];
#pragma unroll
      for (int g = 0; g < 2; ++g) {
        pb[g].u[0] = pk2(s[g][2 * p2][0], s[g][2 * p2][1]);
        pb[g].u[1] = pk2(s[g][2 * p2][2], s[g][2 * p2][3]);
        pb[g].u[2] = pk2(s[g][2 * p2 + 1][0], s[g][2 * p2 + 1][1]);
        pb[g].u[3] = pk2(s[g][2 * p2 + 1][2], s[g][2 * p2 + 1][3]);
      }
      int cc = (p2 * 4 + lq) ^ rx;
#pragma unroll
      for (int mt = 0; mt < 4; ++mt) {
        int row = mt * 16 + lrow;
        bf16x8 vf = *(const bf16x8*)&bufV[(row * 8 + cc) * 8];
#pragma unroll
        for (int g = 0; g < 2; ++g)
          acc[g][mt] = __builtin_amdgcn_mfma_f32_16x16x32_bf16(
              vf, pb[g].v, acc[g][mt], 0, 0, 0);
      }
    }
  }

  // denominators (once, outside loop)
#pragma unroll
  for (int g = 0; g < 2; ++g) {
    rs[g] += __shfl_xor(rs[g], 16);
    rs[g] += __shfl_xor(rs[g], 32);
    if (lq == 0) lout[w * 32 + g * 16 + lrow] = rs[g];
  }

  // O^T partials -> f16 [q][dh]
#pragma unroll
  for (int g = 0; g < 2; ++g)
#pragma unroll
    for (int mt = 0; mt < 4; ++mt) {
      f16x4 o;
#pragma unroll
      for (int r = 0; r < 4; ++r) o[r] = (f16)acc[g][mt][r];
      *(f16x4*)&oout[(w * 32 + g * 16 + lrow) * 64 + mt * 16 + lq * 4] = o;
    }
}

// ---- combine: out = (sum_z O_z) / (sum_z l_z), write bf16 ao ----
__global__ __launch_bounds__(256) void attn_combine(
    const f16* __restrict__ opart, const float* __restrict__ lpart,
    bf16* __restrict__ ao) {
  const int bh = blockIdx.x, qt = blockIdx.y;
  const int b = bh >> 3, h = bh & 7;
  const size_t base = ((size_t)bh * 16 + qt) * ZMAX;
  const int t = threadIdx.x, q = t >> 1, ds = (t & 1) * 32;
  float O[32] = {};
  float lsum = 0.f;
#pragma unroll
  for (int z = 0; z < ZMAX; ++z) {
    float lz = lpart[(base + z) * 128 + q];
    if (lz != 0.f) {
      lsum += lz;
      const f16x8* p = (const f16x8*)&opart[(base + z) * 8192 + q * 64 + ds];
#pragma unroll
      for (int j = 0; j < 4; ++j) {
        f16x8 a = p[j];
#pragma unroll
        for (int r = 0; r < 8; ++r) O[j * 8 + r] += (float)a[r];
      }
    }
  }
  float inv = 1.0f / lsum;
  bf16* dst = &ao[((size_t)(b * QQ + qt * 128 + q)) * DD + h * DHH + ds];
#pragma unroll
  for (int j = 0; j < 4; ++j) {
    bf16x8 o;
#pragma unroll
    for (int r = 0; r < 8; ++r) o[r] = (bf16)(O[j * 8 + r] * inv);
    *(bf16x8*)(dst + j * 8) = o;
  }
}

extern "C" void kernel_launch(void* const* d_in, const int* in_sizes, int n_in,
                              void* d_out, int out_size, void* d_ws, size_t ws_size,
                              hipStream_t stream) {
  const float* queries    = (const float*)d_in[0];
  const float* keys       = (const float*)d_in[1];
  const float* values     = (const float*)d_in[2];
  const int*   valid_lens = (const int*)d_in[3];
  const float* W_q = (const float*)d_in[4];
  const float* W_k = (const float*)d_in[5];
  const float* W_v = (const float*)d_in[6];
  const float* W_o = (const float*)d_in[7];

  const size_t NX = (size_t)BB * QQ * DD;   // 4194304

  bf16* qh = (bf16*)d_ws;       // [B,H,S,DH] (pre-scaled by 1/8*log2e)
  bf16* kh = qh + NX;           // [B,H,S,DH]
  bf16* vt = kh + NX;           // [B,H,DH,S] PV-ready key order
  bf16* ao = vt + NX;           // [B,S,D]
  f16*  opart = (f16*)(ao + NX);              // 32*16*ZMAX*8192 f16 = 16.8 MB
  float* lpart = (float*)(opart + (size_t)32 * 16 * ZMAX * 8192);  // 0.5 MB

  dim3 blk(256);
  const float qscale = 0.125f * 1.44269504088896340736f;  // 1/sqrt(64)*log2e
  proj3<<<dim3(256, 3), blk, 0, stream>>>(queries, W_q, qh, keys, W_k, kh,
                                          values, W_v, vt, qscale);

  attn_split<<<dim3(BB * HH, QQ / 128, ZMAX), blk, 0, stream>>>(
      qh, kh, vt, valid_lens, opart, lpart);
  attn_combine<<<dim3(BB * HH, QQ / 128), blk, 0, stream>>>(opart, lpart, ao);

  proj_o<<<dim3(512), blk, 0, stream>>>(W_o, ao, (float*)d_out);
}

// Round 8
// 185.070 us; speedup vs baseline: 1.0071x; 1.0071x over previous
//
#include <hip/hip_runtime.h>
#include <cstdint>
#include <cstddef>

// Problem constants
#define BB  4
#define QQ  2048
#define SK  2048   // key length
#define DD  512
#define HH  8
#define DHH 64
#define CS  16     // K-tiles (of 64 keys) per attention chunk
#define ZMAX 2     // max chunks (nkt <= 32)

typedef __bf16 bf16;
typedef bf16  bf16x8 __attribute__((ext_vector_type(8)));
typedef bf16  bf16x4 __attribute__((ext_vector_type(4)));
typedef float f32x4  __attribute__((ext_vector_type(4)));
typedef _Float16 f16;
typedef f16   f16x4 __attribute__((ext_vector_type(4)));
typedef f16   f16x8 __attribute__((ext_vector_type(8)));

// ---- async global->LDS 16B copy (wave-uniform base + lane*16 semantics) ----
__device__ __forceinline__ void async16(void* lds, const void* g) {
  __builtin_amdgcn_global_load_lds(
      (const __attribute__((address_space(1))) unsigned int*)g,
      (__attribute__((address_space(3))) unsigned int*)lds, 16, 0, 0);
}

// pack two positive f32 into one u32 of 2 bf16 (truncation) via v_perm_b32
__device__ __forceinline__ uint32_t pk2(float lo, float hi) {
  return __builtin_amdgcn_perm(__builtin_bit_cast(uint32_t, hi),
                               __builtin_bit_cast(uint32_t, lo), 0x07060302u);
}

__device__ __forceinline__ bf16x8 cvt8(const f32x4& a0, const f32x4& a1) {
  bf16x8 o;
  o[0] = (bf16)a0[0]; o[1] = (bf16)a0[1]; o[2] = (bf16)a0[2]; o[3] = (bf16)a0[3];
  o[4] = (bf16)a1[0]; o[5] = (bf16)a1[1]; o[6] = (bf16)a1[2]; o[7] = (bf16)a1[3];
  return o;
}

// ---- GEMM body: D[m][n] = sum_k A[m][k]*B[n][k], K=512, BK=64 ----
// Single LDS buffer, 2 barriers/iter, 32 KB LDS. M-tile = MT*32, N-tile = 128.
// 4 waves (2x2). XOR-swizzled LDS.
// A_F32/B_F32: operand is f32 in global, staged via REGISTER-PREFETCH
// (fetch it+1 during compute of it) + RNE-cvt + ds_write — numerics identical
// to a pre-convert pass. Otherwise bf16 staged via async16.
// NOTE: call this exactly ONCE per kernel (each instantiation owns its own
// static __shared__; two calls would double LDS_Block_Size).
template <int MT, bool A_F32, bool B_F32, typename EpiF>
__device__ __forceinline__ void gemm_body(
    const void* __restrict__ A, const void* __restrict__ B,
    int tM, int tN, EpiF epi_fn) {
  __shared__ __align__(16) bf16 lA[MT * 32 * 64];
  __shared__ __align__(16) bf16 lB[128 * 64];
  const int tid  = threadIdx.x;
  const int l    = tid & 63;
  const int w    = tid >> 6;
  const int lrow = l & 15, lq = l >> 4;
  const int wm = (w >> 1) * (MT * 16), wn = (w & 1) * 64;

  f32x4 pa[MT][2], pb[4][2];
  auto fetchA = [&](int kt) {
#pragma unroll
    for (int j = 0; j < MT; ++j) {
      int c = j * 256 + tid, row = c >> 3, gcc = (c & 7) ^ (row & 7);
      const float* src = (const float*)A + (size_t)(tM + row) * DD + kt + gcc * 8;
      pa[j][0] = *(const f32x4*)src;
      pa[j][1] = *(const f32x4*)(src + 4);
    }
  };
  auto fetchB = [&](int kt) {
#pragma unroll
    for (int j = 0; j < 4; ++j) {
      int c = j * 256 + tid, row = c >> 3, gcc = (c & 7) ^ (row & 7);
      const float* src = (const float*)B + (size_t)(tN + row) * DD + kt + gcc * 8;
      pb[j][0] = *(const f32x4*)src;
      pb[j][1] = *(const f32x4*)(src + 4);
    }
  };

  if (A_F32) fetchA(0);
  if (B_F32) fetchB(0);

  f32x4 acc[MT][4] = {};
  for (int it = 0; it < 8; ++it) {
    const int kt = it * 64;
    if (it) __syncthreads();             // LDS free (prev readers done)
#pragma unroll
    for (int j = 0; j < MT; ++j) {
      int c = j * 256 + tid;
      if (A_F32) {
        *(bf16x8*)&lA[c * 8] = cvt8(pa[j][0], pa[j][1]);
      } else {
        int row = c >> 3, gcc = (c & 7) ^ (row & 7);
        async16(&lA[c * 8], (const bf16*)A + (size_t)(tM + row) * DD + kt + gcc * 8);
      }
    }
#pragma unroll
    for (int j = 0; j < 4; ++j) {
      int c = j * 256 + tid;
      if (B_F32) {
        *(bf16x8*)&lB[c * 8] = cvt8(pb[j][0], pb[j][1]);
      } else {
        int row = c >> 3, gcc = (c & 7) ^ (row & 7);
        async16(&lB[c * 8], (const bf16*)B + (size_t)(tN + row) * DD + kt + gcc * 8);
      }
    }
    __syncthreads();                     // drains vmcnt+lgkm -> LDS valid

    if (it + 1 < 8) {                    // prefetch next f32 tiles into regs
      if (A_F32) fetchA(kt + 64);        // (in flight under the MFMAs below)
      if (B_F32) fetchB(kt + 64);
    }

#pragma unroll
    for (int ks = 0; ks < 2; ++ks) {
      bf16x8 af[MT], bfr[4];
#pragma unroll
      for (int mt = 0; mt < MT; ++mt) {
        int row = wm + mt * 16 + lrow;
        int chunk = row * 8 + ((ks * 4 + lq) ^ (lrow & 7));
        af[mt] = *(const bf16x8*)&lA[chunk * 8];
      }
#pragma unroll
      for (int nt = 0; nt < 4; ++nt) {
        int row = wn + nt * 16 + lrow;
        int chunk = row * 8 + ((ks * 4 + lq) ^ (lrow & 7));
        bfr[nt] = *(const bf16x8*)&lB[chunk * 8];
      }
#pragma unroll
      for (int mt = 0; mt < MT; ++mt)
#pragma unroll
        for (int nt = 0; nt < 4; ++nt)
          acc[mt][nt] = __builtin_amdgcn_mfma_f32_16x16x32_bf16(
              af[mt], bfr[nt], acc[mt][nt], 0, 0, 0);
    }
  }

#pragma unroll
  for (int mt = 0; mt < MT; ++mt)
#pragma unroll
    for (int nt = 0; nt < 4; ++nt) {
      int row0 = tM + wm + mt * 16 + lq * 4;
      int col  = tN + wn + nt * 16 + lrow;
      epi_fn(acc[mt][nt], row0, col);
    }
}

// fused Q/K/V projections from RAW f32 inputs, blockIdx.y selects.
// z<2 (Q,K): SWAPPED orientation, A=W f32 (m=out-dim), B=X f32 (n=token).
//   C rows = out-dim -> 4 consecutive dh per lane -> bf16x4 stores.
// z==2 (V): normal, A=X f32 (m=token), B=W f32. C rows = keys -> bf16x4
//   stores to PV-ready-permuted [B,H,DH,S].
// ONE gemm_body instantiation (unified epilogue, block-uniform z branch).
__global__ __launch_bounds__(256, 3) void proj3(
    const float* __restrict__ xq, const float* __restrict__ wq, bf16* __restrict__ qh,
    const float* __restrict__ xk, const float* __restrict__ wk, bf16* __restrict__ kh,
    const float* __restrict__ xv, const float* __restrict__ wv, bf16* __restrict__ vt,
    float qscale) {
  const int z = blockIdx.y, x = blockIdx.x;
  const float *A, *B;
  bf16* Cout;
  int tM, tN;
  float scale = 1.0f;
  if (z < 2) {
    A = z == 0 ? wq : wk;                // weights: m = out-dim
    B = z == 0 ? xq : xk;                // activations: n = token
    Cout = z == 0 ? qh : kh;
    if (z == 0) scale = qscale;
    tM = (x & 3) * 128; tN = (x >> 2) * 128;
  } else {
    A = xv; B = wv; Cout = vt;
    tM = (x >> 2) * 128; tN = (x & 3) * 128;
  }
  gemm_body<4, true, true>(A, B, tM, tN,
      [&](const f32x4& a, int row0, int col) {
    if (z < 2) {
      int b2 = col >> 11, s = col & 2047;      // token
      int h2 = row0 >> 6, dh0 = row0 & 63;     // out-dim (4 consecutive dh)
      bf16x4 o;
#pragma unroll
      for (int r = 0; r < 4; ++r) o[r] = (bf16)(a[r] * scale);
      *(bf16x4*)&Cout[((size_t)(b2 * HH + h2) * QQ + s) * DHH + dh0] = o;
    } else {
      int b2 = row0 >> 11, s0 = row0 & 2047;   // 4 consecutive keys
      int h2 = col >> 6,  dh = col & 63;
      int tile = s0 >> 6, kk = s0 & 63;
      int g = kk >> 4, a2 = (kk >> 2) & 3;
      int idx0 = ((g >> 1) * 4 + a2) * 8 + (g & 1) * 4;   // PV permutation
      bf16x4 o;
#pragma unroll
      for (int r = 0; r < 4; ++r) o[r] = (bf16)a[r];
      *(bf16x4*)&Cout[((size_t)(b2 * HH + h2) * DHH + dh) * SK + tile * 64 + idx0] = o;
    }
  });
}

// output projection, SWAPPED: A=W_o f32 (m=out-col), B=ao bf16 (n=token).
// C rows = out-cols -> float4 stores to d_out [token][512].
__global__ __launch_bounds__(256, 3) void proj_o(
    const float* __restrict__ wo, const bf16* __restrict__ ao,
    float* __restrict__ Cout) {
  const int x = blockIdx.x;
  int tM = (x & 7) * 64, tN = (x >> 3) * 128;
  gemm_body<2, true, false>(wo, ao, tM, tN,
      [&](const f32x4& a, int row0, int col) {
    *(float4*)&Cout[(size_t)col * DD + row0] = *(const float4*)&a;
  });
}

// ---- Attention, fixed-size chunks: S^T = K·Q^T, no-max softmax ----
// grid (bh, qt=16, z=2). Block = 128 queries (32/wave), chunk = CS 64-key
// tiles. No shuffles/rescale in loop; P packed via v_perm truncation and
// stays in registers; V is PV-ready so its A-frag is one ds_read_b128.
__global__ __launch_bounds__(256, 4) void attn_split(
    const bf16* __restrict__ qh, const bf16* __restrict__ kh,
    const bf16* __restrict__ vt, const int* __restrict__ valid_lens,
    f16* __restrict__ opart, float* __restrict__ lpart) {
  __shared__ __align__(16) bf16 lK[2][64 * 64];   // [key][dh], swizzled
  __shared__ __align__(16) bf16 lV[2][64 * 64];   // [dh][key-permuted], swizzled
  const int tid  = threadIdx.x;
  const int l    = tid & 63;
  const int w    = tid >> 6;
  const int lrow = l & 15, lq = l >> 4;
  const int rx   = lrow & 7;
  const int bh = blockIdx.x;
  const int b = bh >> 3;
  const int qt = blockIdx.y, z = blockIdx.z;
  const int vl  = valid_lens[b];
  const int nkt = (vl + 63) >> 6;
  const int kt0 = z * CS;
  const int kt1 = min(nkt, kt0 + CS);
  const size_t pbase = ((size_t)bh * 16 + qt) * ZMAX + z;
  float* lout = lpart + pbase * 128;
  f16*   oout = opart + pbase * 8192;

  if (kt0 >= kt1) {                      // empty chunk (block-uniform)
    if (tid < 128) lout[tid] = 0.f;
    return;
  }

  const int q0 = qt * 128 + w * 32;
  const bf16* qbase = qh + (size_t)bh * QQ * DHH;
  const bf16* kbase = kh + (size_t)bh * SK * DHH;
  const bf16* vbase = vt + (size_t)bh * DHH * SK;

  // Q fragments (B-operand: n=lane&15=query, k=quad*8+j), 2 query groups
  bf16x8 qf[2][2];
#pragma unroll
  for (int g = 0; g < 2; ++g)
#pragma unroll
    for (int ks = 0; ks < 2; ++ks)
      qf[g][ks] = *(const bf16x8*)
          &qbase[(size_t)(q0 + g * 16 + lrow) * DHH + ks * 32 + lq * 8];

  auto stageKV = [&](int k0, int buf) {
#pragma unroll
    for (int j = 0; j < 2; ++j) {
      int c = j * 256 + tid, row = c >> 3, gcc = (c & 7) ^ (row & 7);
      async16(&lK[buf][c * 8], &kbase[(size_t)(k0 + row) * DHH + gcc * 8]);
    }
#pragma unroll
    for (int j = 0; j < 2; ++j) {
      int c = j * 256 + tid, row = c >> 3, gcc = (c & 7) ^ (row & 7);
      async16(&lV[buf][c * 8], &vbase[(size_t)row * SK + k0 + gcc * 8]);
    }
  };

  f32x4 acc[2][4] = {};                  // O^T[dh=mt*16+lq*4+r][q group g]
  float rs[2] = {0.f, 0.f};

  stageKV(kt0 * 64, kt0 & 1);
  for (int kt = kt0; kt < kt1; ++kt) {
    __syncthreads();                     // drains stage(kt)
    if (kt + 1 < kt1) stageKV((kt + 1) * 64, (kt + 1) & 1);
    const bf16* bufK = lK[kt & 1];
    const bf16* bufV = lV[kt & 1];
    const int k0 = kt * 64;

    // S^T = K · Q^T (A = K rows; kf shared across both query groups)
    f32x4 s[2][4] = {};
#pragma unroll
    for (int ks = 0; ks < 2; ++ks) {
#pragma unroll
      for (int t = 0; t < 4; ++t) {
        int row = t * 16 + lrow;
        int chunkc = row * 8 + ((ks * 4 + lq) ^ rx);
        bf16x8 kf = *(const bf16x8*)&bufK[chunkc * 8];
#pragma unroll
        for (int g = 0; g < 2; ++g)
          s[g][t] = __builtin_amdgcn_mfma_f32_16x16x32_bf16(
              kf, qf[g][ks], s[g][t], 0, 0, 0);
      }
    }

    if (vl < k0 + 64) {                  // partial tile only: mask
#pragma unroll
      for (int t = 0; t < 4; ++t) {
        int kb = k0 + t * 16 + lq * 4;
#pragma unroll
        for (int r = 0; r < 4; ++r)
          if (kb + r >= vl) { s[0][t][r] = -1e30f; s[1][t][r] = -1e30f; }
      }
    }

    // p = exp2(s) directly (|s| small; masked -> exactly 0)
#pragma unroll
    for (int g = 0; g < 2; ++g)
#pragma unroll
      for (int t = 0; t < 4; ++t)
#pragma unroll
        for (int r = 0; r < 4; ++r) {
          float p = __builtin_amdgcn_exp2f(s[g][t][r]);
          rs[g] += p;
          s[g][t][r] = p;
        }

    // O^T += V^T · P  (vt PV-ready; vf shared across query groups)
#pragma unroll
    for (int p2 = 0; p2 < 2; ++p2) {
      union { bf16x8 v; uint32_t u[4]; } pb[2];
#pragma unroll
      for (int g = 0; g < 2; ++g) {
        pb[g].u[0] = pk2(s[g][2 * p2][0], s[g][2 * p2][1]);
        pb[g].u[1] = pk2(s[g][2 * p2][2], s[g][2 * p2][3]);
        pb[g].u[2] = pk2(s[g][2 * p2 + 1][0], s[g][2 * p2 + 1][1]);
        pb[g].u[3] = pk2(s[g][2 * p2 + 1][2], s[g][2 * p2 + 1][3]);
      }
      int cc = (p2 * 4 + lq) ^ rx;
#pragma unroll
      for (int mt = 0; mt < 4; ++mt) {
        int row = mt * 16 + lrow;
        bf16x8 vf = *(const bf16x8*)&bufV[(row * 8 + cc) * 8];
#pragma unroll
        for (int g = 0; g < 2; ++g)
          acc[g][mt] = __builtin_amdgcn_mfma_f32_16x16x32_bf16(
              vf, pb[g].v, acc[g][mt], 0, 0, 0);
      }
    }
  }

  // denominators (once, outside loop)
#pragma unroll
  for (int g = 0; g < 2; ++g) {
    rs[g] += __shfl_xor(rs[g], 16);
    rs[g] += __shfl_xor(rs[g], 32);
    if (lq == 0) lout[w * 32 + g * 16 + lrow] = rs[g];
  }

  // O^T partials -> f16 [q][dh]
#pragma unroll
  for (int g = 0; g < 2; ++g)
#pragma unroll
    for (int mt = 0; mt < 4; ++mt) {
      f16x4 o;
#pragma unroll
      for (int r = 0; r < 4; ++r) o[r] = (f16)acc[g][mt][r];
      *(f16x4*)&oout[(w * 32 + g * 16 + lrow) * 64 + mt * 16 + lq * 4] = o;
    }
}

// ---- combine: out = (sum_z O_z) / (sum_z l_z), write bf16 ao ----
__global__ __launch_bounds__(256) void attn_combine(
    const f16* __restrict__ opart, const float* __restrict__ lpart,
    bf16* __restrict__ ao) {
  const int bh = blockIdx.x, qt = blockIdx.y;
  const int b = bh >> 3, h = bh & 7;
  const size_t base = ((size_t)bh * 16 + qt) * ZMAX;
  const int t = threadIdx.x, q = t >> 1, ds = (t & 1) * 32;
  float O[32] = {};
  float lsum = 0.f;
#pragma unroll
  for (int z = 0; z < ZMAX; ++z) {
    float lz = lpart[(base + z) * 128 + q];
    if (lz != 0.f) {
      lsum += lz;
      const f16x8* p = (const f16x8*)&opart[(base + z) * 8192 + q * 64 + ds];
#pragma unroll
      for (int j = 0; j < 4; ++j) {
        f16x8 a = p[j];
#pragma unroll
        for (int r = 0; r < 8; ++r) O[j * 8 + r] += (float)a[r];
      }
    }
  }
  float inv = 1.0f / lsum;
  bf16* dst = &ao[((size_t)(b * QQ + qt * 128 + q)) * DD + h * DHH + ds];
#pragma unroll
  for (int j = 0; j < 4; ++j) {
    bf16x8 o;
#pragma unroll
    for (int r = 0; r < 8; ++r) o[r] = (bf16)(O[j * 8 + r] * inv);
    *(bf16x8*)(dst + j * 8) = o;
  }
}

extern "C" void kernel_launch(void* const* d_in, const int* in_sizes, int n_in,
                              void* d_out, int out_size, void* d_ws, size_t ws_size,
                              hipStream_t stream) {
  const float* queries    = (const float*)d_in[0];
  const float* keys       = (const float*)d_in[1];
  const float* values     = (const float*)d_in[2];
  const int*   valid_lens = (const int*)d_in[3];
  const float* W_q = (const float*)d_in[4];
  const float* W_k = (const float*)d_in[5];
  const float* W_v = (const float*)d_in[6];
  const float* W_o = (const float*)d_in[7];

  const size_t NX = (size_t)BB * QQ * DD;   // 4194304

  bf16* qh = (bf16*)d_ws;       // [B,H,S,DH] (pre-scaled by 1/8*log2e)
  bf16* kh = qh + NX;           // [B,H,S,DH]
  bf16* vt = kh + NX;           // [B,H,DH,S] PV-ready key order
  bf16* ao = vt + NX;           // [B,S,D]
  f16*  opart = (f16*)(ao + NX);              // 32*16*ZMAX*8192 f16 = 16.8 MB
  float* lpart = (float*)(opart + (size_t)32 * 16 * ZMAX * 8192);  // 0.5 MB

  dim3 blk(256);
  const float qscale = 0.125f * 1.44269504088896340736f;  // 1/sqrt(64)*log2e
  proj3<<<dim3(256, 3), blk, 0, stream>>>(queries, W_q, qh, keys, W_k, kh,
                                          values, W_v, vt, qscale);

  attn_split<<<dim3(BB * HH, QQ / 128, ZMAX), blk, 0, stream>>>(
      qh, kh, vt, valid_lens, opart, lpart);
  attn_combine<<<dim3(BB * HH, QQ / 128), blk, 0, stream>>>(opart, lpart, ao);

  proj_o<<<dim3(512), blk, 0, stream>>>(W_o, ao, (float*)d_out);
}